// Round 1
// baseline (92693.341 us; speedup 1.0000x reference)
//
#include <hip/hip_runtime.h>
#include <stdint.h>

#define NB     256
#define NT     256
#define TMAX   2048
#define EPROJS 1024
#define DUNITS 512
#define EMBED  512
#define JOINT  512
#define ODIM   10000

// workspace layout (bytes)
#define WS_CNTU  0
#define WS_CNTP  128
#define WS_UPRT  256                       // float uprt[2][8][512]  (32 KB)
#define WS_PACK  (WS_UPRT + 2*8*JOINT*4)   // u64 pack[256]
#define WS_S     (WS_PACK + NB*8)          // float s[256]
#define WS_Y     (WS_S + NB*4)             // float y[512]
#define WS_HP    65536                     // float hp[2048*512] (4 MB)

__device__ __forceinline__ float aloadf(const float* p){
  return __hip_atomic_load(p, __ATOMIC_RELAXED, __HIP_MEMORY_SCOPE_AGENT);
}
__device__ __forceinline__ void astoref(float* p, float v){
  __hip_atomic_store(p, v, __ATOMIC_RELAXED, __HIP_MEMORY_SCOPE_AGENT);
}
__device__ __forceinline__ unsigned long long aloadu64(const unsigned long long* p){
  return __hip_atomic_load(p, __ATOMIC_RELAXED, __HIP_MEMORY_SCOPE_AGENT);
}
__device__ __forceinline__ void astoreu64(unsigned long long* p, unsigned long long v){
  __hip_atomic_store(p, v, __ATOMIC_RELAXED, __HIP_MEMORY_SCOPE_AGENT);
}
__device__ __forceinline__ uint32_t aloadu32(const uint32_t* p){
  return __hip_atomic_load(p, __ATOMIC_RELAXED, __HIP_MEMORY_SCOPE_AGENT);
}

__device__ __forceinline__ uint32_t ordbits(float f){
  uint32_t u = __float_as_uint(f);
  return (u & 0x80000000u) ? ~u : (u | 0x80000000u);
}
__device__ __forceinline__ float unordbits(uint32_t o){
  uint32_t u = (o & 0x80000000u) ? (o & 0x7fffffffu) : ~o;
  return __uint_as_float(u);
}
__device__ __forceinline__ float sigmoidf_(float x){ return 1.0f/(1.0f+expf(-x)); }

__device__ __forceinline__ float wredsum(float v){
  #pragma unroll
  for (int o=32;o>0;o>>=1) v += __shfl_xor(v, o);
  return v;
}
__device__ __forceinline__ unsigned long long wredmax64(unsigned long long v){
  #pragma unroll
  for (int o=32;o>0;o>>=1){ unsigned long long x = __shfl_xor(v, o); v = (x>v)?x:v; }
  return v;
}

#define LOAD8(dst, baseptr) { const float4* _p=(const float4*)(baseptr); \
  float4 _a=_p[0], _b=_p[1]; \
  dst[0]=_a.x; dst[1]=_a.y; dst[2]=_a.z; dst[3]=_a.w; \
  dst[4]=_b.x; dst[5]=_b.y; dst[6]=_b.z; dst[7]=_b.w; }

__global__ void rnnt_init(uint32_t* cntU, uint32_t* cntP, float* uprt){
  if (threadIdx.x == 0){ *cntU = 0u; *cntP = 0u; }
  for (int i = threadIdx.x; i < 2*8*JOINT; i += blockDim.x) uprt[i] = 0.0f;
}

__global__ void __launch_bounds__(NT, 1)
rnnt_decode(const float* __restrict__ h,    const float* __restrict__ embed,
            const float* __restrict__ W_ih, const float* __restrict__ W_hh,
            const float* __restrict__ b_ih, const float* __restrict__ b_hh,
            const float* __restrict__ W_enc,const float* __restrict__ b_enc,
            const float* __restrict__ W_dec,const float* __restrict__ W_out,
            const float* __restrict__ b_out,
            float* __restrict__ out,
            uint32_t* cntU, uint32_t* cntP,
            float* uprt, unsigned long long* packs, float* sarr,
            float* ybuf, float* hp)
{
  const int b    = blockIdx.x;
  const int tid  = threadIdx.x;
  const int lane = tid & 63;
  const int w    = tid >> 6;

  __shared__ float lds_h[8][EPROJS];      // 32 KB, setup only
  __shared__ float z_l[JOINT];
  __shared__ float y_l[DUNITS];
  __shared__ float e_l[EMBED];
  __shared__ float g_l[8];
  __shared__ unsigned long long red_pk[4];
  __shared__ float red_s[4];
  __shared__ float ybc[2];
  __shared__ unsigned long long bpacks;

  // ---------------- register-resident weight slices ----------------
  float wout[10][8]; float bo[10]; int rowid[10]; bool rvalid[10];
  #pragma unroll
  for (int q=0;q<10;q++){
    const int slot = 4*q + w;          // 10 slots per wave
    const int row  = slot*NB + b;
    rowid[q] = row; rvalid[q] = (row < ODIM);
    if (rvalid[q]){
      LOAD8(wout[q], W_out + (size_t)row*JOINT + lane*8);
      bo[q] = b_out[row];
    } else {
      #pragma unroll
      for (int j=0;j<8;j++) wout[q][j]=0.0f;
      bo[q]=0.0f;
    }
  }
  const int j0 = 2*b, j1 = 2*b+1;
  const int r0 = 512*w + j0, r1 = 512*w + j1;   // gate rows for wave w (i,f,g,o order)
  float wih0[8], wih1[8], whh0[8], whh1[8];
  LOAD8(wih0, W_ih + (size_t)r0*EMBED  + lane*8);
  LOAD8(wih1, W_ih + (size_t)r1*EMBED  + lane*8);
  LOAD8(whh0, W_hh + (size_t)r0*DUNITS + lane*8);
  LOAD8(whh1, W_hh + (size_t)r1*DUNITS + lane*8);
  const float bias0 = b_ih[r0] + b_hh[r0];
  const float bias1 = b_ih[r1] + b_hh[r1];
  // W_dec^T fragments: this thread owns u-indices k=tid and k=tid+256
  const float wd0a = W_dec[(size_t)tid*DUNITS + j0];
  const float wd1a = W_dec[(size_t)tid*DUNITS + j1];
  const float wd0b = W_dec[(size_t)(tid+NT)*DUNITS + j0];
  const float wd1b = W_dec[(size_t)(tid+NT)*DUNITS + j1];

  // ---------------- h_proj = h @ W_enc^T + b_enc  (block b: t-rows 8b..8b+7) ----------------
  #pragma unroll
  for (int r=0;r<8;r++){
    const float4 hv = *(const float4*)(h + (size_t)(8*b + r)*EPROJS + tid*4);
    *(float4*)&lds_h[r][tid*4] = hv;
  }
  __syncthreads();
  for (int p=0;p<2;p++){
    const int j = p*NT + tid;          // output column (W_enc row)
    float acc[8] = {0,0,0,0,0,0,0,0};
    const float4* wrow = (const float4*)(W_enc + (size_t)j*EPROJS);
    for (int k4=0;k4<EPROJS/4;k4++){
      const float4 wv = wrow[k4];
      #pragma unroll
      for (int t8=0;t8<8;t8++){
        const float4 hv = *(const float4*)&lds_h[t8][k4*4];  // wave-broadcast LDS read
        acc[t8] = fmaf(wv.x,hv.x, fmaf(wv.y,hv.y, fmaf(wv.z,hv.z, fmaf(wv.w,hv.w, acc[t8]))));
      }
    }
    const float be = b_enc[j];
    #pragma unroll
    for (int t8=0;t8<8;t8++)
      astoref(&hp[(size_t)(8*b+t8)*JOINT + j], acc[t8] + be);
  }

  // ---------------- initial LSTM step (x=0, h=0, c=0) ----------------
  float c_st0=0.f, c_st1=0.f, y_st0=0.f, y_st1=0.f;
  if (tid==0){
    float gi = b_ih[j0]      + b_hh[j0];
    float gf = b_ih[512+j0]  + b_hh[512+j0];  (void)gf;
    float gg = b_ih[1024+j0] + b_hh[1024+j0];
    float go = b_ih[1536+j0] + b_hh[1536+j0];
    c_st0 = sigmoidf_(gi)*tanhf(gg);
    y_st0 = sigmoidf_(go)*tanhf(c_st0);
    gi = b_ih[j1]      + b_hh[j1];
    gg = b_ih[1024+j1] + b_hh[1024+j1];
    go = b_ih[1536+j1] + b_hh[1536+j1];
    c_st1 = sigmoidf_(gi)*tanhf(gg);
    y_st1 = sigmoidf_(go)*tanhf(c_st1);
    astoref(&ybuf[j0], y_st0); astoref(&ybuf[j1], y_st1);
    ybc[0]=y_st0; ybc[1]=y_st1;
  }
  __syncthreads();
  { // scatter u for t=0 into parity 0 (zeroed by init kernel)
    const float yy0=ybc[0], yy1=ybc[1];
    float* dst = uprt + (b>>5)*JOINT;
    atomicAdd(&dst[tid],    wd0a*yy0 + wd1a*yy1);
    atomicAdd(&dst[tid+NT], wd0b*yy0 + wd1b*yy1);
  }
  __threadfence();
  __syncthreads();
  if (tid==0) atomicAdd(cntU, 1u);

  // ---------------- decode loop ----------------
  float score = 0.0f;
  float v0=0.f, v1=0.f;
  for (int t=0;t<TMAX;t++){
    // ===== Phase B: logits, argmax/logsumexp partials, v = W_hh@y =====
    if (tid==0){
      const uint32_t tgt = (uint32_t)(t+1)*NB;
      while (aloadu32(cntU) < tgt) __builtin_amdgcn_s_sleep(2);
    }
    __syncthreads();
    {
      const int k0=2*tid, k1=2*tid+1;
      const float ya = aloadf(&ybuf[k0]), yb = aloadf(&ybuf[k1]);
      y_l[k0]=ya; y_l[k1]=yb;
      const float* up = uprt + (t&1)*(8*JOINT);
      float u0=0.f, u1=0.f;
      #pragma unroll
      for (int g=0; g<8; g++){
        u0 += aloadf(&up[g*JOINT + k0]);
        u1 += aloadf(&up[g*JOINT + k1]);
      }
      const float h0v = hp[(size_t)t*JOINT + k0];
      const float h1v = hp[(size_t)t*JOINT + k1];
      z_l[k0] = tanhf(h0v + u0);
      z_l[k1] = tanhf(h1v + u1);
    }
    __syncthreads();
    float zr[8], yr[8];
    #pragma unroll
    for (int j=0;j<8;j++){ zr[j]=z_l[lane*8+j]; yr[j]=y_l[lane*8+j]; }
    { // v rows (W_hh @ y) for this wave's two gate rows
      float a=0.f, c=0.f;
      #pragma unroll
      for (int j=0;j<8;j++){ a=fmaf(whh0[j],yr[j],a); c=fmaf(whh1[j],yr[j],c); }
      v0 = wredsum(a); v1 = wredsum(c);
    }
    float lg[10];
    #pragma unroll
    for (int q=0;q<10;q++){
      float a=0.f;
      #pragma unroll
      for (int j=0;j<8;j++) a = fmaf(wout[q][j], zr[j], a);
      lg[q] = wredsum(a) + bo[q];
    }
    unsigned long long pk = 0ULL;
    #pragma unroll
    for (int q=0;q<10;q++){
      if (rvalid[q]){
        const unsigned long long key =
          ((unsigned long long)ordbits(lg[q])<<32) | (uint32_t)(~(uint32_t)rowid[q]);
        pk = (key>pk)?key:pk;
      }
    }
    const float mw = unordbits((uint32_t)(pk>>32));
    float sw = 0.f;
    #pragma unroll
    for (int q=0;q<10;q++) if (rvalid[q]) sw += __expf(lg[q]-mw);
    if (lane==0){ red_pk[w]=pk; red_s[w]=sw; }
    __syncthreads();
    if (tid==0){
      unsigned long long bp = red_pk[0];
      #pragma unroll
      for (int i=1;i<4;i++) bp = (red_pk[i]>bp)?red_pk[i]:bp;
      const float mb = unordbits((uint32_t)(bp>>32));
      float S=0.f;
      #pragma unroll
      for (int i=0;i<4;i++) S += red_s[i]*__expf(unordbits((uint32_t)(red_pk[i]>>32)) - mb);
      astoreu64(&packs[b], bp);
      astoref(&sarr[b], S);
    }
    __threadfence();
    __syncthreads();
    if (tid==0) atomicAdd(cntP, 1u);

    // ===== Phase CA: global argmax, score, LSTM update, u scatter =====
    if (tid==0){
      const uint32_t tgt = (uint32_t)(t+1)*NB;
      while (aloadu32(cntP) < tgt) __builtin_amdgcn_s_sleep(2);
    }
    __syncthreads();
    if (tid<16) astoref(&uprt[(t&1)*(8*JOINT) + b*16 + tid], 0.0f); // recycle consumed parity
    const unsigned long long pki = aloadu64(&packs[tid]);
    const float si = aloadf(&sarr[tid]);
    {
      const unsigned long long g64 = wredmax64(pki);
      if (lane==0) red_pk[w]=g64;
    }
    __syncthreads();
    if (tid==0){
      unsigned long long bp = red_pk[0];
      #pragma unroll
      for (int i=1;i<4;i++) bp = (red_pk[i]>bp)?red_pk[i]:bp;
      bpacks = bp;
    }
    __syncthreads();
    const unsigned long long best = bpacks;
    const int   pred    = (int)(~(uint32_t)best);
    const float mstar   = unordbits((uint32_t)(best>>32));
    const bool  emitted = (pred != 0);
    if (b==0){ // score path (only block 0)
      float term = si * __expf(unordbits((uint32_t)(pki>>32)) - mstar);
      term = wredsum(term);
      if (lane==0) red_s[w]=term;
      __syncthreads();
      if (tid==0){
        const float S = red_s[0]+red_s[1]+red_s[2]+red_s[3];
        const float logp = -logf(S);
        if (emitted) score += logp;
        out[t] = emitted ? (float)pred : 0.0f;
      }
    }
    { // stage embedding row
      const float* er = embed + (size_t)pred*EMBED;
      e_l[2*tid]   = er[2*tid];
      e_l[2*tid+1] = er[2*tid+1];
    }
    __syncthreads();
    float a0=0.f, a1=0.f;
    {
      float er8[8];
      #pragma unroll
      for (int j=0;j<8;j++) er8[j]=e_l[lane*8+j];
      #pragma unroll
      for (int j=0;j<8;j++){ a0=fmaf(wih0[j],er8[j],a0); a1=fmaf(wih1[j],er8[j],a1); }
      a0 = wredsum(a0); a1 = wredsum(a1);
    }
    if (lane==0){ g_l[2*w]=v0+a0+bias0; g_l[2*w+1]=v1+a1+bias1; }
    __syncthreads();
    if (tid==0){
      const float gi0=g_l[0], gf0=g_l[2], gg0=g_l[4], go0=g_l[6];
      const float gi1=g_l[1], gf1=g_l[3], gg1=g_l[5], go1=g_l[7];
      const float cn0 = sigmoidf_(gf0)*c_st0 + sigmoidf_(gi0)*tanhf(gg0);
      const float yn0 = sigmoidf_(go0)*tanhf(cn0);
      const float cn1 = sigmoidf_(gf1)*c_st1 + sigmoidf_(gi1)*tanhf(gg1);
      const float yn1 = sigmoidf_(go1)*tanhf(cn1);
      if (emitted){ c_st0=cn0; y_st0=yn0; c_st1=cn1; y_st1=yn1; }
      ybc[0]=y_st0; ybc[1]=y_st1;
      astoref(&ybuf[j0], y_st0);
      astoref(&ybuf[j1], y_st1);
    }
    __syncthreads();
    {
      const float yy0=ybc[0], yy1=ybc[1];
      float* dst = uprt + ((t+1)&1)*(8*JOINT) + (b>>5)*JOINT;
      atomicAdd(&dst[tid],    wd0a*yy0 + wd1a*yy1);
      atomicAdd(&dst[tid+NT], wd0b*yy0 + wd1b*yy1);
    }
    __threadfence();
    __syncthreads();
    if (tid==0) atomicAdd(cntU, 1u);
  }
  if (b==0 && tid==0) out[TMAX] = score;
}

extern "C" void kernel_launch(void* const* d_in, const int* in_sizes, int n_in,
                              void* d_out, int out_size, void* d_ws, size_t ws_size,
                              hipStream_t stream)
{
  const float* h     = (const float*)d_in[0];
  const float* embed = (const float*)d_in[1];
  const float* W_ih  = (const float*)d_in[2];
  const float* W_hh  = (const float*)d_in[3];
  const float* b_ih  = (const float*)d_in[4];
  const float* b_hh  = (const float*)d_in[5];
  const float* W_enc = (const float*)d_in[6];
  const float* b_enc = (const float*)d_in[7];
  const float* W_dec = (const float*)d_in[8];
  const float* W_out = (const float*)d_in[9];
  const float* b_out = (const float*)d_in[10];
  float* out = (float*)d_out;
  char* ws = (char*)d_ws;
  uint32_t* cntU = (uint32_t*)(ws + WS_CNTU);
  uint32_t* cntP = (uint32_t*)(ws + WS_CNTP);
  float* uprt = (float*)(ws + WS_UPRT);
  unsigned long long* packs = (unsigned long long*)(ws + WS_PACK);
  float* sarr = (float*)(ws + WS_S);
  float* ybuf = (float*)(ws + WS_Y);
  float* hp   = (float*)(ws + WS_HP);

  hipLaunchKernelGGL(rnnt_init, dim3(1), dim3(NT), 0, stream, cntU, cntP, uprt);
  hipLaunchKernelGGL(rnnt_decode, dim3(NB), dim3(NT), 0, stream,
                     h, embed, W_ih, W_hh, b_ih, b_hh, W_enc, b_enc, W_dec, W_out, b_out,
                     out, cntU, cntP, uprt, packs, sarr, ybuf, hp);
}

// Round 2
// 18703.711 us; speedup vs baseline: 4.9559x; 4.9559x over previous
//
#include <hip/hip_runtime.h>
#include <stdint.h>

typedef unsigned long long u64;
typedef uint32_t u32;

#define NB     256
#define NT     256
#define TMAX   2048
#define EPROJS 1024
#define DUNITS 512
#define EMBED  512
#define JOINT  512
#define ODIM   10000

#define N_LSTM 32          // blocks 0..31: LSTM, 16 y-elems each
#define DEC0   32          // blocks 32..47: dec, 32 u-rows each
#define CONS0  48          // blocks 48..255: consumers (W_out)
#define N_CONS 208
#define MAGIC  0xD07ED07Eu

// workspace layout (bytes)
#define WS_YB   0          // u64[512]  tagged y      (4 KB)
#define WS_UD   4096       // u64[512]  tagged u      (4 KB)
#define WS_PK   8192       // u64[208]  tagged packs
#define WS_SA   10240      // u64[208]  tagged sums
#define WS_DN   12288      // u32[256]  setup-done flags
#define WS_HP   16384      // float[2048*512] h_proj  (4 MB)

__device__ __forceinline__ float aloadf(const float* p){
  return __hip_atomic_load(p, __ATOMIC_RELAXED, __HIP_MEMORY_SCOPE_AGENT);
}
__device__ __forceinline__ void astoref(float* p, float v){
  __hip_atomic_store(p, v, __ATOMIC_RELAXED, __HIP_MEMORY_SCOPE_AGENT);
}
__device__ __forceinline__ u64 aloadu64(const u64* p){
  return __hip_atomic_load(p, __ATOMIC_RELAXED, __HIP_MEMORY_SCOPE_AGENT);
}
__device__ __forceinline__ void astoreu64(u64* p, u64 v){
  __hip_atomic_store(p, v, __ATOMIC_RELAXED, __HIP_MEMORY_SCOPE_AGENT);
}
__device__ __forceinline__ u32 aloadu32(const u32* p){
  return __hip_atomic_load(p, __ATOMIC_RELAXED, __HIP_MEMORY_SCOPE_AGENT);
}
__device__ __forceinline__ void astoreu32(u32* p, u32 v){
  __hip_atomic_store(p, v, __ATOMIC_RELAXED, __HIP_MEMORY_SCOPE_AGENT);
}

__device__ __forceinline__ u32 ordbits(float f){
  u32 u = __float_as_uint(f);
  return (u & 0x80000000u) ? ~u : (u | 0x80000000u);
}
__device__ __forceinline__ float unordbits(u32 o){
  u32 u = (o & 0x80000000u) ? (o & 0x7fffffffu) : ~o;
  return __uint_as_float(u);
}
__device__ __forceinline__ float sigmoidf_(float x){ return 1.0f/(1.0f+expf(-x)); }

__device__ __forceinline__ float wredsum(float v){
  #pragma unroll
  for (int o=32;o>0;o>>=1) v += __shfl_xor(v, o);
  return v;
}
__device__ __forceinline__ u64 wredmax64(u64 v){
  #pragma unroll
  for (int o=32;o>0;o>>=1){ u64 x = __shfl_xor(v, o); v = (x>v)?x:v; }
  return v;
}

#define LOAD8(dst, baseptr) { const float4* _p=(const float4*)(baseptr); \
  float4 _a=_p[0], _b=_p[1]; \
  dst[0]=_a.x; dst[1]=_a.y; dst[2]=_a.z; dst[3]=_a.w; \
  dst[4]=_b.x; dst[5]=_b.y; dst[6]=_b.z; dst[7]=_b.w; }

#define LDS8(dst, base) { float4 _a=*(const float4*)(base); \
  float4 _b=*(const float4*)((base)+4); \
  dst[0]=_a.x; dst[1]=_a.y; dst[2]=_a.z; dst[3]=_a.w; \
  dst[4]=_b.x; dst[5]=_b.y; dst[6]=_b.z; dst[7]=_b.w; }

__global__ void rnnt_init(char* ws){
  // zero the 16 KB control region (tagged arrays + done flags)
  u32* p = (u32*)ws;
  for (int i = threadIdx.x; i < 4096; i += blockDim.x) p[i] = 0u;
}

__global__ void __launch_bounds__(NT, 1)
rnnt_decode(const float* __restrict__ h,    const float* __restrict__ embed,
            const float* __restrict__ W_ih, const float* __restrict__ W_hh,
            const float* __restrict__ b_ih, const float* __restrict__ b_hh,
            const float* __restrict__ W_enc,const float* __restrict__ b_enc,
            const float* __restrict__ W_dec,const float* __restrict__ W_out,
            const float* __restrict__ b_out,
            float* __restrict__ out, char* __restrict__ ws)
{
  const int b    = blockIdx.x;
  const int tid  = threadIdx.x;
  const int lane = tid & 63;
  const int w    = tid >> 6;

  u64*   ybuf = (u64*)(ws + WS_YB);
  u64*   udec = (u64*)(ws + WS_UD);
  u64*   packs= (u64*)(ws + WS_PK);
  u64*   sarr = (u64*)(ws + WS_SA);
  u32*   done = (u32*)(ws + WS_DN);
  float* hp   = (float*)(ws + WS_HP);

  __shared__ float smem[8192];                 // 32 KB, multi-purpose
  float* PL = smem;                            // [64][68] partial sums
  float* EL = &smem[4416];                     // e row   (512)
  float* YL = &smem[4928];                     // y       (512)
  float* ZL = &smem[5440];                     // z       (512)
  float* GL = &smem[5952];                     // gates   (64)
  u64*   R64= (u64*)&smem[6016];               // 4 u64 reduce slots
  float* RF = &smem[6024];                     // 4 float reduce slots

  // ================= setup: hp = h @ W_enc^T + b_enc (rows 8b..8b+7) =========
  {
    float (*lds_h)[EPROJS] = (float(*)[EPROJS])smem;
    #pragma unroll
    for (int r=0;r<8;r++){
      const float4 hv = *(const float4*)(h + (size_t)(8*b + r)*EPROJS + tid*4);
      *(float4*)&lds_h[r][tid*4] = hv;
    }
    __syncthreads();
    for (int p=0;p<2;p++){
      const int j = p*NT + tid;
      float acc[8] = {0,0,0,0,0,0,0,0};
      const float4* wrow = (const float4*)(W_enc + (size_t)j*EPROJS);
      for (int k4=0;k4<EPROJS/4;k4++){
        const float4 wv = wrow[k4];
        #pragma unroll
        for (int t8=0;t8<8;t8++){
          const float4 hv = *(const float4*)&lds_h[t8][k4*4];
          acc[t8] = fmaf(wv.x,hv.x, fmaf(wv.y,hv.y, fmaf(wv.z,hv.z, fmaf(wv.w,hv.w, acc[t8]))));
        }
      }
      const float be = b_enc[j];
      #pragma unroll
      for (int t8=0;t8<8;t8++)
        astoref(&hp[(size_t)(8*b+t8)*JOINT + j], acc[t8] + be);
    }
    asm volatile("s_waitcnt vmcnt(0)" ::: "memory");
    if (tid==0) astoreu32(&done[b], MAGIC);
    __syncthreads();   // smem reuse fence
  }

  // ============================ role: LSTM ===================================
  if (b < N_LSTM){
    const int d = b;
    float wih[16][8], whh[16][8];
    #pragma unroll
    for (int q=0;q<16;q++){
      const int gr = w*DUNITS + 16*d + q;       // wave w = gate type (i,f,g,o)
      LOAD8(wih[q], W_ih + (size_t)gr*EMBED  + lane*8);
      LOAD8(whh[q], W_hh + (size_t)gr*DUNITS + lane*8);
    }
    float bias_r = 0.0f;
    if (tid < 64){
      const int gr = (tid>>4)*DUNITS + 16*d + (tid&15);
      bias_r = b_ih[gr] + b_hh[gr];
    }
    // bootstrap state (threads 0..15)
    float c_st = 0.0f, y_st = 0.0f;
    if (tid < 16){
      const int j = 16*d + tid;
      const float gi = b_ih[j]            + b_hh[j];
      const float gg = b_ih[2*DUNITS + j] + b_hh[2*DUNITS + j];
      const float go = b_ih[3*DUNITS + j] + b_hh[3*DUNITS + j];
      c_st = sigmoidf_(gi)*tanhf(gg);
      y_st = sigmoidf_(go)*tanhf(c_st);
      astoreu64(&ybuf[j], ((u64)1u<<32) | (u64)__float_as_uint(y_st));
    }

    for (int t=0;t<TMAX;t++){
      const u32 tg = (u32)(t+1);
      // --- poll y state (tag t+1), stage to LDS ---
      u64 ya, yb;
      for(;;){
        ya = aloadu64(&ybuf[2*tid]); yb = aloadu64(&ybuf[2*tid+1]);
        const int ok = ((u32)(ya>>32)==tg) & ((u32)(yb>>32)==tg);
        if (__syncthreads_and(ok)) break;
      }
      YL[2*tid]   = __uint_as_float((u32)ya);
      YL[2*tid+1] = __uint_as_float((u32)yb);
      __syncthreads();
      float y8[8]; LDS8(y8, &YL[8*lane]);
      float vp[16];                              // v = W_hh @ y  (off critical path)
      #pragma unroll
      for (int q=0;q<16;q++){
        float a=0.f;
        #pragma unroll
        for (int k=0;k<8;k++) a = fmaf(whh[q][k], y8[k], a);
        vp[q] = a;
      }
      // --- poll packs -> pred ---
      u64 pk = 0;
      for(;;){
        if (tid < N_CONS) pk = aloadu64(&packs[tid]);
        const int ok = (tid < N_CONS) ? ((u32)(pk>>48)==tg) : 1;
        if (__syncthreads_and(ok)) break;
      }
      { u64 m = wredmax64(pk); if (lane==0) R64[w]=m; }
      __syncthreads();
      if (tid==0){
        u64 bb=R64[0];
        #pragma unroll
        for (int i=1;i<4;i++) bb = (R64[i]>bb)?R64[i]:bb;
        R64[0]=bb;
      }
      __syncthreads();
      const u64 best = R64[0];
      const int pred = (int)((~(u32)best) & 0xFFFFu);
      const int emitted = (pred != 0);
      __syncthreads();
      // --- stage embedding row ---
      const float2 ev = *(const float2*)(embed + (size_t)pred*EMBED + 2*tid);
      EL[2*tid] = ev.x; EL[2*tid+1] = ev.y;
      __syncthreads();
      float e8[8]; LDS8(e8, &EL[8*lane]);
      #pragma unroll
      for (int q=0;q<16;q++){
        float a = vp[q];
        #pragma unroll
        for (int k=0;k<8;k++) a = fmaf(wih[q][k], e8[k], a);
        PL[(w*16+q)*68 + lane] = a;
      }
      __syncthreads();
      if (tid < 64){
        const float* row = &PL[tid*68];
        float s = bias_r;
        #pragma unroll
        for (int k4=0;k4<16;k4++){
          const float4 v4 = *(const float4*)&row[4*k4];
          s += v4.x + v4.y + v4.z + v4.w;
        }
        GL[tid] = s;
      }
      __syncthreads();
      if (tid < 16){
        const float gi=GL[tid], gf=GL[16+tid], gg=GL[32+tid], go=GL[48+tid];
        const float cn = sigmoidf_(gf)*c_st + sigmoidf_(gi)*tanhf(gg);
        const float yn = sigmoidf_(go)*tanhf(cn);
        if (emitted){ c_st = cn; y_st = yn; }
        astoreu64(&ybuf[16*d + tid], ((u64)(tg+1)<<32) | (u64)__float_as_uint(y_st));
      }
    }
  }
  // ============================ role: DEC ====================================
  else if (b < CONS0){
    const int dd = b - DEC0;
    float wdec[8][8];
    #pragma unroll
    for (int q=0;q<8;q++){
      const int r = 32*dd + 8*w + q;
      LOAD8(wdec[q], W_dec + (size_t)r*DUNITS + lane*8);
    }
    for (int t=0;t<TMAX;t++){
      const u32 tg = (u32)(t+1);
      u64 ya, yb;
      for(;;){
        ya = aloadu64(&ybuf[2*tid]); yb = aloadu64(&ybuf[2*tid+1]);
        const int ok = ((u32)(ya>>32)==tg) & ((u32)(yb>>32)==tg);
        if (__syncthreads_and(ok)) break;
      }
      YL[2*tid]   = __uint_as_float((u32)ya);
      YL[2*tid+1] = __uint_as_float((u32)yb);
      __syncthreads();
      float y8[8]; LDS8(y8, &YL[8*lane]);
      #pragma unroll
      for (int q=0;q<8;q++){
        float a=0.f;
        #pragma unroll
        for (int k=0;k<8;k++) a = fmaf(wdec[q][k], y8[k], a);
        PL[(8*w+q)*68 + lane] = a;
      }
      __syncthreads();
      if (tid < 32){
        const float* row = &PL[tid*68];
        float s = 0.f;
        #pragma unroll
        for (int k4=0;k4<16;k4++){
          const float4 v4 = *(const float4*)&row[4*k4];
          s += v4.x + v4.y + v4.z + v4.w;
        }
        astoreu64(&udec[32*dd + tid], ((u64)tg<<32) | (u64)__float_as_uint(s));
      }
      __syncthreads();   // PL reuse fence
    }
  }
  // ============================ role: CONSUMER ===============================
  else {
    const int cb = b - CONS0;
    const int rowstart = (cb<16) ? cb*49 : 784 + (cb-16)*48;
    const int rowcnt   = (cb<16) ? 49 : 48;
    float wout[13][8];
    #pragma unroll
    for (int q=0;q<13;q++){
      const int s = 13*w + q;
      if (s < rowcnt){
        LOAD8(wout[q], W_out + (size_t)(rowstart+s)*JOINT + lane*8);
      } else {
        #pragma unroll
        for (int k=0;k<8;k++) wout[q][k]=0.f;
      }
    }
    float my_bo = 0.f; int my_row = 0; bool my_val = false;
    if (tid < rowcnt){ my_val = true; my_row = rowstart + tid; my_bo = b_out[my_row]; }

    // wait for all hp writers
    for(;;){
      const int ok = (aloadu32(&done[tid]) == MAGIC);
      if (__syncthreads_and(ok)) break;
    }

    float score = 0.0f;
    for (int t=0;t<TMAX;t++){
      const u32 tg = (u32)(t+1);
      // --- poll u ---
      u64 ua, ub;
      for(;;){
        ua = aloadu64(&udec[2*tid]); ub = aloadu64(&udec[2*tid+1]);
        const int ok = ((u32)(ua>>32)==tg) & ((u32)(ub>>32)==tg);
        if (__syncthreads_and(ok)) break;
      }
      const float u0 = __uint_as_float((u32)ua);
      const float u1 = __uint_as_float((u32)ub);
      const float h0 = aloadf(&hp[(size_t)t*JOINT + 2*tid]);
      const float h1 = aloadf(&hp[(size_t)t*JOINT + 2*tid + 1]);
      ZL[2*tid]   = tanhf(h0 + u0);
      ZL[2*tid+1] = tanhf(h1 + u1);
      __syncthreads();
      float z8[8]; LDS8(z8, &ZL[8*lane]);
      #pragma unroll
      for (int q=0;q<13;q++){
        float a=0.f;
        #pragma unroll
        for (int k=0;k<8;k++) a = fmaf(wout[q][k], z8[k], a);
        PL[(13*w+q)*68 + lane] = a;
      }
      __syncthreads();
      u64 key = 0; float lg = 0.f;
      if (tid < 52){
        const float* row = &PL[tid*68];
        float s = my_bo;
        #pragma unroll
        for (int k4=0;k4<16;k4++){
          const float4 v4 = *(const float4*)&row[4*k4];
          s += v4.x + v4.y + v4.z + v4.w;
        }
        lg = s;
        if (my_val) key = ((u64)ordbits(lg)<<16) | (u64)(0xFFFFu & ~(u32)my_row);
      }
      if (w == 0){
        const u64 bk = wredmax64(key);
        const float mw = unordbits((u32)(bk>>16));
        const float e  = my_val ? __expf(lg - mw) : 0.f;
        const float sw = wredsum(e);
        if (lane == 0){
          astoreu64(&sarr[cb],  ((u64)tg<<32) | (u64)__float_as_uint(sw));
          astoreu64(&packs[cb], ((u64)tg<<48) | bk);
        }
      }
      if (b == CONS0){
        u64 pk = 0, sa = 0;
        for(;;){
          if (tid < N_CONS){ pk = aloadu64(&packs[tid]); sa = aloadu64(&sarr[tid]); }
          const int ok = (tid < N_CONS) ?
            (((u32)(pk>>48)==tg) & ((u32)(sa>>32)==tg)) : 1;
          if (__syncthreads_and(ok)) break;
        }
        { u64 m = wredmax64(pk); if (lane==0) R64[w]=m; }
        __syncthreads();
        if (tid==0){
          u64 bb=R64[0];
          #pragma unroll
          for (int i=1;i<4;i++) bb = (R64[i]>bb)?R64[i]:bb;
          R64[0]=bb;
        }
        __syncthreads();
        const u64 best = R64[0];
        const float mstar = unordbits((u32)(best>>16));
        float term = (tid < N_CONS) ?
          __uint_as_float((u32)sa) * __expf(unordbits((u32)(pk>>16)) - mstar) : 0.f;
        term = wredsum(term);
        if (lane==0) RF[w]=term;
        __syncthreads();
        if (tid==0){
          const float S = RF[0]+RF[1]+RF[2]+RF[3];
          const int pred = (int)((~(u32)best) & 0xFFFFu);
          if (pred != 0) score += -logf(S);
          out[t] = (float)pred;
        }
        __syncthreads();
      } else {
        __syncthreads();   // PL reuse fence
      }
    }
    if (b == CONS0 && tid == 0) out[TMAX] = score;
  }
}

extern "C" void kernel_launch(void* const* d_in, const int* in_sizes, int n_in,
                              void* d_out, int out_size, void* d_ws, size_t ws_size,
                              hipStream_t stream)
{
  const float* h     = (const float*)d_in[0];
  const float* embed = (const float*)d_in[1];
  const float* W_ih  = (const float*)d_in[2];
  const float* W_hh  = (const float*)d_in[3];
  const float* b_ih  = (const float*)d_in[4];
  const float* b_hh  = (const float*)d_in[5];
  const float* W_enc = (const float*)d_in[6];
  const float* b_enc = (const float*)d_in[7];
  const float* W_dec = (const float*)d_in[8];
  const float* W_out = (const float*)d_in[9];
  const float* b_out = (const float*)d_in[10];
  float* out = (float*)d_out;
  char* ws = (char*)d_ws;

  hipLaunchKernelGGL(rnnt_init, dim3(1), dim3(NT), 0, stream, ws);
  hipLaunchKernelGGL(rnnt_decode, dim3(NB), dim3(NT), 0, stream,
                     h, embed, W_ih, W_hh, b_ih, b_hh, W_enc, b_enc, W_dec, W_out, b_out,
                     out, ws);
}